// Round 6
// baseline (191.729 us; speedup 1.0000x reference)
//
#include <hip/hip_runtime.h>
#include <math.h>

// B=4, T=1024, C=D=1024 fixed by reference setup_inputs.
constexpr int B = 4, T = 1024, C = 1024, D = 1024;
constexpr int M = B * T;
constexpr float K_CLAMP = 60.0f, K_EPS = 1e-8f;

typedef _Float16 half8 __attribute__((ext_vector_type(8)));
typedef _Float16 half4v __attribute__((ext_vector_type(4)));
typedef float float4v __attribute__((ext_vector_type(4)));

// async global->LDS, 16B/lane. LDS dst is wave-uniform base; HW adds lane*16.
typedef __attribute__((address_space(3))) unsigned int lds_uint;
typedef const __attribute__((address_space(1))) unsigned int g_uint;
__device__ __forceinline__ void load_lds16(const void* g, void* l) {
    __builtin_amdgcn_global_load_lds((g_uint*)(size_t)g,
                                     (lds_uint*)(unsigned int)(size_t)l, 16, 0, 0);
}

__device__ __forceinline__ float fast_sigmoid(float v) {
    return __builtin_amdgcn_rcpf(1.0f + __expf(-v));
}

// ============================================================================
// convert: fused prep (blocks 0..4095) + weight fp32->fp16 (blocks 4096..8191)
// ============================================================================
__global__ __launch_bounds__(256) void convert_kernel(
    const float* __restrict__ x, const float* __restrict__ tmk,
    const float* __restrict__ tmv, const float* __restrict__ tmr,
    _Float16* __restrict__ ak, _Float16* __restrict__ av, _Float16* __restrict__ ar,
    const float* __restrict__ w0, const float* __restrict__ w1,
    const float* __restrict__ w2, const float* __restrict__ w3,
    _Float16* __restrict__ h0, _Float16* __restrict__ h1,
    _Float16* __restrict__ h2, _Float16* __restrict__ h3)
{
    const int bid = blockIdx.x;
    if (bid < 4096) {
        const int gid = bid * 256 + threadIdx.x;
        const int m = gid >> 8;
        const int cg = (gid & 255) << 2;
        const int t = m & (T - 1);
        float4 xv = *(const float4*)(x + (size_t)m * C + cg);
        float4 xp = make_float4(0.f, 0.f, 0.f, 0.f);
        if (t != 0) xp = *(const float4*)(x + (size_t)(m - 1) * C + cg);
        float4 k4 = *(const float4*)(tmk + cg);
        float4 v4 = *(const float4*)(tmv + cg);
        float4 r4 = *(const float4*)(tmr + cg);
        half4v ok, ov, orr;
        ok[0] = (_Float16)(xv.x * k4.x + xp.x * (1.f - k4.x));
        ok[1] = (_Float16)(xv.y * k4.y + xp.y * (1.f - k4.y));
        ok[2] = (_Float16)(xv.z * k4.z + xp.z * (1.f - k4.z));
        ok[3] = (_Float16)(xv.w * k4.w + xp.w * (1.f - k4.w));
        ov[0] = (_Float16)(xv.x * v4.x + xp.x * (1.f - v4.x));
        ov[1] = (_Float16)(xv.y * v4.y + xp.y * (1.f - v4.y));
        ov[2] = (_Float16)(xv.z * v4.z + xp.z * (1.f - v4.z));
        ov[3] = (_Float16)(xv.w * v4.w + xp.w * (1.f - v4.w));
        orr[0] = (_Float16)(xv.x * r4.x + xp.x * (1.f - r4.x));
        orr[1] = (_Float16)(xv.y * r4.y + xp.y * (1.f - r4.y));
        orr[2] = (_Float16)(xv.z * r4.z + xp.z * (1.f - r4.z));
        orr[3] = (_Float16)(xv.w * r4.w + xp.w * (1.f - r4.w));
        *(half4v*)(ak + (size_t)m * C + cg) = ok;
        *(half4v*)(av + (size_t)m * C + cg) = ov;
        *(half4v*)(ar + (size_t)m * C + cg) = orr;
    } else {
        const int q = bid - 4096;
        const int mat = q >> 10;
        const float* s = mat == 0 ? w0 : mat == 1 ? w1 : mat == 2 ? w2 : w3;
        _Float16* d = mat == 0 ? h0 : mat == 1 ? h1 : mat == 2 ? h2 : h3;
        const int gid = (q & 1023) * 256 + threadIdx.x;
        float4 v = *(const float4*)(s + (size_t)gid * 4);
        half4v o;
        o[0] = (_Float16)v.x; o[1] = (_Float16)v.y;
        o[2] = (_Float16)v.z; o[3] = (_Float16)v.w;
        *(half4v*)(d + (size_t)gid * 4) = o;
    }
}

// ============================================================================
// Unified GEMM: 64x128 tile, BK=64 — EXACT round-4 gemm_out K-loop (proven
// through full harness twice), templated on MODE for the epilogue only.
// LDS row = 8 chunks of 16B; chunk c of row r at halfs r*64 + ((c+r)&7)*8.
// grid (M/64, D/128) = (64, 8) = 512 blocks (2/CU). Wave tile 32m x 64n.
// MODE 0: exp(min(k,60)) -> fp16 [B,D,T]; 1: copy -> fp16 [B,D,T];
// MODE 2: sigmoid -> fp16 [B,D,T];       3: fp32 [M,D] (no activation).
// ============================================================================
template<int MODE>
__global__ __launch_bounds__(256) void gemm64x128_kernel(
    const _Float16* __restrict__ Abase, const _Float16* __restrict__ Wbase,
    void* __restrict__ Yout)
{
    __shared__ __align__(16) char smem[33792];  // K-loop: 24576 B; repack below
    _Float16* lA = (_Float16*)smem;             // 64*64 halfs = 8 KB
    _Float16* lB = (_Float16*)(smem + 8192);    // 128*64 halfs = 16 KB
    const int tid = threadIdx.x, wave = tid >> 6, lane = tid & 63;
    const int quad = lane >> 4, l15 = lane & 15;
    const int wm = wave & 1, wn = wave >> 1;
    const int mtile = blockIdx.x * 64;
    const int ntile = blockIdx.y * 128;
    const _Float16* A = Abase + (size_t)mtile * C;
    const _Float16* W = Wbase + (size_t)ntile * C;

    const int rS = tid >> 3, oS = tid & 7, cS = (oS - rS) & 7;
    const _Float16* pA = A + (size_t)rS * C + cS * 8;
    const _Float16* pB = W + (size_t)rS * C + cS * 8;

    int aOff[2], bOff[4];
#pragma unroll
    for (int i = 0; i < 2; i++) {
        int mm = wm * 32 + i * 16 + l15;
        aOff[i] = mm * 64 + (((quad + mm) & 7) << 3);
    }
#pragma unroll
    for (int j = 0; j < 4; j++) {
        int nn = wn * 64 + j * 16 + l15;
        bOff[j] = nn * 64 + (((quad + nn) & 7) << 3);
    }

    float4v acc[2][4] = {};
    for (int it = 0; it < 16; it++) {            // 16 * 64 = K=1024
#pragma unroll
        for (int n = 0; n < 2; n++)              // A: 512 slots
            load_lds16(pA + (size_t)n * 32 * C, lA + (n * 256 + wave * 64) * 8);
#pragma unroll
        for (int n = 0; n < 4; n++)              // B: 1024 slots
            load_lds16(pB + (size_t)n * 32 * C, lB + (n * 256 + wave * 64) * 8);
        pA += 64; pB += 64;
        __syncthreads();
        half8 af[2], bf[4];
#pragma unroll
        for (int i = 0; i < 2; i++) af[i] = *(const half8*)(lA + aOff[i]);
#pragma unroll
        for (int j = 0; j < 4; j++) bf[j] = *(const half8*)(lB + bOff[j]);
#pragma unroll
        for (int i = 0; i < 2; i++)
#pragma unroll
            for (int j = 0; j < 4; j++)
                acc[i][j] = __builtin_amdgcn_mfma_f32_16x16x32_f16(af[i], bf[j], acc[i][j], 0, 0, 0);
#pragma unroll
        for (int i = 0; i < 2; i++) af[i] = *(const half8*)(lA + (aOff[i] ^ 32));
#pragma unroll
        for (int j = 0; j < 4; j++) bf[j] = *(const half8*)(lB + (bOff[j] ^ 32));
#pragma unroll
        for (int i = 0; i < 2; i++)
#pragma unroll
            for (int j = 0; j < 4; j++)
                acc[i][j] = __builtin_amdgcn_mfma_f32_16x16x32_f16(af[i], bf[j], acc[i][j], 0, 0, 0);
        __syncthreads();
    }

    if (MODE == 3) {
        // repack fp32 tile [m][d] pad 132 floats, full-row float4 stores
        float* ftile = (float*)smem;             // 64 x 132 = 33792 B
#pragma unroll
        for (int i = 0; i < 2; i++)
#pragma unroll
            for (int j = 0; j < 4; j++) {
                const int dl = wn * 64 + j * 16 + l15;
#pragma unroll
                for (int r = 0; r < 4; r++) {
                    const int ml = wm * 32 + i * 16 + quad * 4 + r;
                    ftile[ml * 132 + dl] = acc[i][j][r];
                }
            }
        __syncthreads();
        float* out = (float*)Yout;
#pragma unroll
        for (int s = 0; s < 8; s++) {
            const int cid = s * 256 + tid;       // 2048 float4 chunks
            const int ml = cid >> 5, dc = (cid & 31) << 2;
            float4 v = *(const float4*)(ftile + ml * 132 + dc);
            *(float4*)(out + (size_t)(mtile + ml) * D + ntile + dc) = v;
        }
    } else {
        // activation -> repack fp16 tile [d][t] pad 72 -> b128 row stores [B,D,T]
        _Float16* htile = (_Float16*)smem;       // 128 x 72 halfs = 18432 B
#pragma unroll
        for (int i = 0; i < 2; i++)
#pragma unroll
            for (int j = 0; j < 4; j++) {
                const int dl = wn * 64 + j * 16 + l15;
                const int tl = wm * 32 + i * 16 + quad * 4;
                half4v o;
#pragma unroll
                for (int r = 0; r < 4; r++) {
                    float v = acc[i][j][r];
                    if (MODE == 0) v = __expf(fminf(v, K_CLAMP));
                    else if (MODE == 2) v = fast_sigmoid(v);
                    o[r] = (_Float16)v;
                }
                *(half4v*)(htile + dl * 72 + tl) = o;
            }
        __syncthreads();
        const int bidx = mtile >> 10;
        const int tglob0 = mtile & (T - 1);
        _Float16* Y = (_Float16*)Yout;
#pragma unroll
        for (int s = 0; s < 4; s++) {
            const int cid = s * 256 + tid;       // 1024 chunks of 16B
            const int dl = cid >> 3, tc = (cid & 7) << 3;
            half8 v = *(const half8*)(htile + dl * 72 + tc);
            *(half8*)(Y + (((size_t)(bidx * D + ntile + dl)) << 10) + tglob0 + tc) = v;
        }
    }
}

// ============================================================================
// scan_tr: fused scan + transpose (round-4 proven version, pad 1026).
// 1024 threads = 16 waves = 16 channels; wave scans its channel over T,
// transpose through LDS, midT [B,T,C] out.
// ============================================================================
__global__ __launch_bounds__(1024) void scan_tr_kernel(
    const _Float16* __restrict__ kc, const _Float16* __restrict__ vv,
    const _Float16* __restrict__ sr, const float* __restrict__ td,
    const float* __restrict__ tf, _Float16* __restrict__ midT)
{
    __shared__ _Float16 L[16 * 1026];
    const int tid = threadIdx.x;
    const int w = tid >> 6, lane = tid & 63;
    const int bq = blockIdx.x >> 6;
    const int c0 = (blockIdx.x & 63) << 4;
    const int c = c0 + w;
    const float wfac = expf(-expf(td[c]));
    const float ef = expf(tf[c]);
    const size_t base = (((size_t)(bq * C + c)) << 10) + lane * 16;

    half8 kA = *(const half8*)(kc + base), kB = *(const half8*)(kc + base + 8);
    half8 vA = *(const half8*)(vv + base), vB = *(const half8*)(vv + base + 8);
    half8 sA = *(const half8*)(sr + base), sB = *(const half8*)(sr + base + 8);
    float kcl[16], vl[16], srl[16];
#pragma unroll
    for (int i = 0; i < 8; i++) {
        kcl[i] = (float)kA[i]; kcl[8 + i] = (float)kB[i];
        vl[i]  = (float)vA[i]; vl[8 + i]  = (float)vB[i];
        srl[i] = (float)sA[i]; srl[8 + i] = (float)sB[i];
    }
    float ua = 0.f, ub = 0.f;
#pragma unroll
    for (int i = 0; i < 16; i++) {
        float kv = kcl[i] * vl[i];
        ua = fmaf(wfac, ua, kv);
        ub = fmaf(wfac, ub, kcl[i]);
    }
    float w2 = wfac * wfac, w4 = w2 * w2, w8 = w4 * w4, w16 = w8 * w8;
    float f = w16, sa = ua, sb = ub;
#pragma unroll
    for (int off = 1; off < 64; off <<= 1) {
        float pa = __shfl_up(sa, off);
        float pb = __shfl_up(sb, off);
        if (lane >= off) { sa = fmaf(f, pa, sa); sb = fmaf(f, pb, sb); }
        f = f * f;
    }
    float a0 = __shfl_up(sa, 1);
    float b0 = __shfl_up(sb, 1);
    if (lane == 0) { a0 = 0.f; b0 = 0.f; }
    half8 o0, o1;
#pragma unroll
    for (int i = 0; i < 16; i++) {
        float kv = kcl[i] * vl[i];
        float wkv = fmaf(ef, kv, a0);
        float wk = fmaf(ef, kcl[i], b0) + K_EPS;
        float o = srl[i] * (wkv / wk);
        if (i < 8) o0[i] = (_Float16)o; else o1[i - 8] = (_Float16)o;
        a0 = fmaf(wfac, a0, kv);
        b0 = fmaf(wfac, b0, kcl[i]);
    }
    *(half8*)(L + w * 1026 + lane * 16) = o0;
    *(half8*)(L + w * 1026 + lane * 16 + 8) = o1;
    __syncthreads();
    half8 g0, g1;
#pragma unroll
    for (int cc = 0; cc < 8; cc++)  g0[cc] = L[cc * 1026 + tid];
#pragma unroll
    for (int cc = 0; cc < 8; cc++)  g1[cc] = L[(cc + 8) * 1026 + tid];
    _Float16* dst = midT + (((size_t)(bq * T + tid)) << 10) + c0;
    *(half8*)(dst) = g0;
    *(half8*)(dst + 8) = g1;
}

extern "C" void kernel_launch(void* const* d_in, const int* in_sizes, int n_in,
                              void* d_out, int out_size, void* d_ws, size_t ws_size,
                              hipStream_t stream) {
    const float* xq  = (const float*)d_in[0];
    const float* td  = (const float*)d_in[3];
    const float* tf  = (const float*)d_in[4];
    const float* tmk = (const float*)d_in[5];
    const float* tmv = (const float*)d_in[6];
    const float* tmr = (const float*)d_in[7];
    const float* Wk  = (const float*)d_in[8];
    const float* Wv  = (const float*)d_in[9];
    const float* Wr  = (const float*)d_in[10];
    const float* Wo  = (const float*)d_in[11];
    float* out = (float*)d_out;

    const size_t MC = (size_t)M * C;
    char* ws = (char*)d_ws;
    _Float16* ak   = (_Float16*)(ws);
    _Float16* av   = (_Float16*)(ws + MC * 2);
    _Float16* ar   = (_Float16*)(ws + MC * 4);
    _Float16* wk16 = (_Float16*)(ws + MC * 6);
    _Float16* wv16 = wk16 + (size_t)D * C;
    _Float16* wr16 = wv16 + (size_t)D * C;
    _Float16* wo16 = wr16 + (size_t)D * C;
    _Float16* kc16 = (_Float16*)(ws + MC * 6 + (size_t)D * C * 8);
    _Float16* vv16 = kc16 + MC;
    _Float16* sr16 = vv16 + MC;
    _Float16* midT = ak;   // ak dead after gemm<0>; scan_tr runs after all 3

    dim3 gg(M / 64, D / 128);   // 512 blocks per GEMM
    convert_kernel<<<dim3(8192), dim3(256), 0, stream>>>(
        xq, tmk, tmv, tmr, ak, av, ar, Wk, Wv, Wr, Wo, wk16, wv16, wr16, wo16);
    gemm64x128_kernel<0><<<gg, dim3(256), 0, stream>>>(ak, wk16, kc16);
    gemm64x128_kernel<1><<<gg, dim3(256), 0, stream>>>(av, wv16, vv16);
    gemm64x128_kernel<2><<<gg, dim3(256), 0, stream>>>(ar, wr16, sr16);
    scan_tr_kernel<<<dim3(B * C / 16), dim3(1024), 0, stream>>>(
        kc16, vv16, sr16, td, tf, midT);
    gemm64x128_kernel<3><<<gg, dim3(256), 0, stream>>>(midT, wo16, out);
}

// Round 8
// 179.424 us; speedup vs baseline: 1.0686x; 1.0686x over previous
//
#include <hip/hip_runtime.h>
#include <math.h>

// B=4, T=1024, C=D=1024 fixed by reference setup_inputs.
constexpr int B = 4, T = 1024, C = 1024, D = 1024;
constexpr int M = B * T;
constexpr float K_CLAMP = 60.0f, K_EPS = 1e-8f;

typedef _Float16 half8 __attribute__((ext_vector_type(8)));
typedef _Float16 half4v __attribute__((ext_vector_type(4)));
typedef float float4v __attribute__((ext_vector_type(4)));

// async global->LDS, 16B/lane. LDS dst is wave-uniform base; HW adds lane*16.
typedef __attribute__((address_space(3))) unsigned int lds_uint;
typedef const __attribute__((address_space(1))) unsigned int g_uint;
__device__ __forceinline__ void load_lds16(const void* g, void* l) {
    __builtin_amdgcn_global_load_lds((g_uint*)(size_t)g,
                                     (lds_uint*)(unsigned int)(size_t)l, 16, 0, 0);
}

__device__ __forceinline__ float fast_sigmoid(float v) {
    return __builtin_amdgcn_rcpf(1.0f + __expf(-v));
}

// ============================================================================
// convert: fused prep (blocks 0..4095) + weight fp32->fp16 (blocks 4096..8191)
// (r4/r6-proven, unchanged)
// ============================================================================
__global__ __launch_bounds__(256) void convert_kernel(
    const float* __restrict__ x, const float* __restrict__ tmk,
    const float* __restrict__ tmv, const float* __restrict__ tmr,
    _Float16* __restrict__ ak, _Float16* __restrict__ av, _Float16* __restrict__ ar,
    const float* __restrict__ w0, const float* __restrict__ w1,
    const float* __restrict__ w2, const float* __restrict__ w3,
    _Float16* __restrict__ h0, _Float16* __restrict__ h1,
    _Float16* __restrict__ h2, _Float16* __restrict__ h3)
{
    const int bid = blockIdx.x;
    if (bid < 4096) {
        const int gid = bid * 256 + threadIdx.x;
        const int m = gid >> 8;
        const int cg = (gid & 255) << 2;
        const int t = m & (T - 1);
        float4 xv = *(const float4*)(x + (size_t)m * C + cg);
        float4 xp = make_float4(0.f, 0.f, 0.f, 0.f);
        if (t != 0) xp = *(const float4*)(x + (size_t)(m - 1) * C + cg);
        float4 k4 = *(const float4*)(tmk + cg);
        float4 v4 = *(const float4*)(tmv + cg);
        float4 r4 = *(const float4*)(tmr + cg);
        half4v ok, ov, orr;
        ok[0] = (_Float16)(xv.x * k4.x + xp.x * (1.f - k4.x));
        ok[1] = (_Float16)(xv.y * k4.y + xp.y * (1.f - k4.y));
        ok[2] = (_Float16)(xv.z * k4.z + xp.z * (1.f - k4.z));
        ok[3] = (_Float16)(xv.w * k4.w + xp.w * (1.f - k4.w));
        ov[0] = (_Float16)(xv.x * v4.x + xp.x * (1.f - v4.x));
        ov[1] = (_Float16)(xv.y * v4.y + xp.y * (1.f - v4.y));
        ov[2] = (_Float16)(xv.z * v4.z + xp.z * (1.f - v4.z));
        ov[3] = (_Float16)(xv.w * v4.w + xp.w * (1.f - v4.w));
        orr[0] = (_Float16)(xv.x * r4.x + xp.x * (1.f - r4.x));
        orr[1] = (_Float16)(xv.y * r4.y + xp.y * (1.f - r4.y));
        orr[2] = (_Float16)(xv.z * r4.z + xp.z * (1.f - r4.z));
        orr[3] = (_Float16)(xv.w * r4.w + xp.w * (1.f - r4.w));
        *(half4v*)(ak + (size_t)m * C + cg) = ok;
        *(half4v*)(av + (size_t)m * C + cg) = ov;
        *(half4v*)(ar + (size_t)m * C + cg) = orr;
    } else {
        const int q = bid - 4096;
        const int mat = q >> 10;
        const float* s = mat == 0 ? w0 : mat == 1 ? w1 : mat == 2 ? w2 : w3;
        _Float16* d = mat == 0 ? h0 : mat == 1 ? h1 : mat == 2 ? h2 : h3;
        const int gid = (q & 1023) * 256 + threadIdx.x;
        float4 v = *(const float4*)(s + (size_t)gid * 4);
        half4v o;
        o[0] = (_Float16)v.x; o[1] = (_Float16)v.y;
        o[2] = (_Float16)v.z; o[3] = (_Float16)v.w;
        *(half4v*)(d + (size_t)gid * 4) = o;
    }
}

// ============================================================================
// gemm_in: fused k/v/r, 256x128 tile, BK=64, 512 threads (8 waves of 64x64).
// LDS row = 8 chunks of 16B; chunk c of row r at halfs r*64 + ((c+r)&7)*8.
// grid (16, 24): mat = y>>3, ntile = (y&7)*128, mtile = x*256.
// Epilogue: activation -> 2-phase LDS repack (t-halves of 128) -> b128 rows.
// ============================================================================
__global__ __launch_bounds__(512, 4) void gemm_in_kernel(
    const _Float16* __restrict__ ak, const _Float16* __restrict__ av, const _Float16* __restrict__ ar,
    const _Float16* __restrict__ wk, const _Float16* __restrict__ wv, const _Float16* __restrict__ wr,
    _Float16* __restrict__ kc, _Float16* __restrict__ vv, _Float16* __restrict__ sr)
{
    __shared__ __align__(16) char smem[49152];
    _Float16* lA = (_Float16*)smem;             // 256*64 halfs = 32 KB
    _Float16* lB = (_Float16*)(smem + 32768);   // 128*64 halfs = 16 KB
    const int tid = threadIdx.x, wave = tid >> 6, lane = tid & 63;
    const int quad = lane >> 4, l15 = lane & 15;
    const int wm = wave & 3, wn = wave >> 2;    // 4 m-positions x 2 n-positions
    const int mat = blockIdx.y >> 3;
    const int ntile = (blockIdx.y & 7) * 128;
    const int mtile = blockIdx.x * 256;
    const _Float16* A = (mat == 0 ? ak : mat == 1 ? av : ar) + (size_t)mtile * C;
    const _Float16* W = (mat == 0 ? wk : mat == 1 ? wv : wr) + (size_t)ntile * C;

    // staging: slot g = n*512 + tid; row = n*64 + (tid>>3); chunk = ((tid&7)-(tid>>3))&7
    const int rS = tid >> 3, oS = tid & 7, cS = (oS - rS) & 7;
    const _Float16* pA = A + (size_t)rS * C + cS * 8;
    const _Float16* pB = W + (size_t)rS * C + cS * 8;

    int aOff[4], bOff[4];
#pragma unroll
    for (int i = 0; i < 4; i++) {
        int mm = wm * 64 + i * 16 + l15;
        aOff[i] = mm * 64 + (((quad + mm) & 7) << 3);
        int nn = wn * 64 + i * 16 + l15;
        bOff[i] = nn * 64 + (((quad + nn) & 7) << 3);
    }

    float4v acc[4][4] = {};
    for (int it = 0; it < 16; it++) {            // 16 * 64 = K=1024
#pragma unroll
        for (int n = 0; n < 4; n++)              // A: 2048 slots
            load_lds16(pA + (size_t)n * 64 * C, lA + (n * 512 + wave * 64) * 8);
#pragma unroll
        for (int n = 0; n < 2; n++)              // B: 1024 slots
            load_lds16(pB + (size_t)n * 64 * C, lB + (n * 512 + wave * 64) * 8);
        pA += 64; pB += 64;
        __syncthreads();
        half8 af[4], bf[4];
#pragma unroll
        for (int i = 0; i < 4; i++) af[i] = *(const half8*)(lA + aOff[i]);
#pragma unroll
        for (int j = 0; j < 4; j++) bf[j] = *(const half8*)(lB + bOff[j]);
#pragma unroll
        for (int i = 0; i < 4; i++)
#pragma unroll
            for (int j = 0; j < 4; j++)
                acc[i][j] = __builtin_amdgcn_mfma_f32_16x16x32_f16(af[i], bf[j], acc[i][j], 0, 0, 0);
#pragma unroll
        for (int i = 0; i < 4; i++) af[i] = *(const half8*)(lA + (aOff[i] ^ 32));
#pragma unroll
        for (int j = 0; j < 4; j++) bf[j] = *(const half8*)(lB + (bOff[j] ^ 32));
#pragma unroll
        for (int i = 0; i < 4; i++)
#pragma unroll
            for (int j = 0; j < 4; j++)
                acc[i][j] = __builtin_amdgcn_mfma_f32_16x16x32_f16(af[i], bf[j], acc[i][j], 0, 0, 0);
        __syncthreads();
    }

    // epilogue: 2 phases over t-halves; htile [128 d][136] halfs = 34816 B
    _Float16* htile = (_Float16*)smem;
    const int bidx = mtile >> 10;
    const int tbase = mtile & (T - 1);
    _Float16* Y = mat == 0 ? kc : mat == 1 ? vv : sr;
#pragma unroll
    for (int p = 0; p < 2; p++) {
        if ((wm >> 1) == p) {
            const int tl0 = (wm & 1) * 64;
#pragma unroll
            for (int i = 0; i < 4; i++)
#pragma unroll
                for (int j = 0; j < 4; j++) {
                    const int dl = wn * 64 + j * 16 + l15;
                    const int tl = tl0 + i * 16 + quad * 4;
                    half4v o;
#pragma unroll
                    for (int r = 0; r < 4; r++) {
                        float v = acc[i][j][r];
                        if (mat == 0) v = __expf(fminf(v, K_CLAMP));
                        else if (mat == 2) v = fast_sigmoid(v);
                        o[r] = (_Float16)v;
                    }
                    *(half4v*)(htile + dl * 136 + tl) = o;
                }
        }
        __syncthreads();
        // store 128 d-rows x 128 t-halfs = 128 rows x 16 chunks of 16B = 2048
#pragma unroll
        for (int s = 0; s < 4; s++) {
            const int cid = s * 512 + tid;
            const int dl = cid >> 4, tc = (cid & 15) << 3;   // FIX: 16 chunks/row
            half8 v = *(const half8*)(htile + dl * 136 + tc);
            *(half8*)(Y + (((size_t)(bidx * D + ntile + dl)) << 10)
                        + tbase + p * 128 + tc) = v;
        }
        __syncthreads();
    }
}

// ============================================================================
// gemm_out: 64x128 tile, BK=64 (r4/r6-proven). grid (64, 8) = 512 blocks.
// ============================================================================
__global__ __launch_bounds__(256) void gemm_out_kernel(
    const _Float16* __restrict__ midT, const _Float16* __restrict__ wo,
    float* __restrict__ out)
{
    __shared__ __align__(16) char smem[33792];  // K-loop: 24576 B; repack 64*132*4
    _Float16* lA = (_Float16*)smem;             // 64*64 halfs = 8 KB
    _Float16* lB = (_Float16*)(smem + 8192);    // 128*64 halfs = 16 KB
    const int tid = threadIdx.x, wave = tid >> 6, lane = tid & 63;
    const int quad = lane >> 4, l15 = lane & 15;
    const int wm = wave & 1, wn = wave >> 1;
    const int mtile = blockIdx.x * 64;
    const int ntile = blockIdx.y * 128;
    const _Float16* A = midT + (size_t)mtile * C;
    const _Float16* W = wo + (size_t)ntile * C;

    const int rS = tid >> 3, oS = tid & 7, cS = (oS - rS) & 7;
    const _Float16* pA = A + (size_t)rS * C + cS * 8;
    const _Float16* pB = W + (size_t)rS * C + cS * 8;

    int aOff[2], bOff[4];
#pragma unroll
    for (int i = 0; i < 2; i++) {
        int mm = wm * 32 + i * 16 + l15;
        aOff[i] = mm * 64 + (((quad + mm) & 7) << 3);
    }
#pragma unroll
    for (int j = 0; j < 4; j++) {
        int nn = wn * 64 + j * 16 + l15;
        bOff[j] = nn * 64 + (((quad + nn) & 7) << 3);
    }

    float4v acc[2][4] = {};
    for (int it = 0; it < 16; it++) {
#pragma unroll
        for (int n = 0; n < 2; n++)
            load_lds16(pA + (size_t)n * 32 * C, lA + (n * 256 + wave * 64) * 8);
#pragma unroll
        for (int n = 0; n < 4; n++)
            load_lds16(pB + (size_t)n * 32 * C, lB + (n * 256 + wave * 64) * 8);
        pA += 64; pB += 64;
        __syncthreads();
        half8 af[2], bf[4];
#pragma unroll
        for (int i = 0; i < 2; i++) af[i] = *(const half8*)(lA + aOff[i]);
#pragma unroll
        for (int j = 0; j < 4; j++) bf[j] = *(const half8*)(lB + bOff[j]);
#pragma unroll
        for (int i = 0; i < 2; i++)
#pragma unroll
            for (int j = 0; j < 4; j++)
                acc[i][j] = __builtin_amdgcn_mfma_f32_16x16x32_f16(af[i], bf[j], acc[i][j], 0, 0, 0);
#pragma unroll
        for (int i = 0; i < 2; i++) af[i] = *(const half8*)(lA + (aOff[i] ^ 32));
#pragma unroll
        for (int j = 0; j < 4; j++) bf[j] = *(const half8*)(lB + (bOff[j] ^ 32));
#pragma unroll
        for (int i = 0; i < 2; i++)
#pragma unroll
            for (int j = 0; j < 4; j++)
                acc[i][j] = __builtin_amdgcn_mfma_f32_16x16x32_f16(af[i], bf[j], acc[i][j], 0, 0, 0);
        __syncthreads();
    }
    float* ftile = (float*)smem;                 // 64 x 132 floats
#pragma unroll
    for (int i = 0; i < 2; i++)
#pragma unroll
        for (int j = 0; j < 4; j++) {
            const int dl = wn * 64 + j * 16 + l15;
#pragma unroll
            for (int r = 0; r < 4; r++) {
                const int ml = wm * 32 + i * 16 + quad * 4 + r;
                ftile[ml * 132 + dl] = acc[i][j][r];
            }
        }
    __syncthreads();
#pragma unroll
    for (int s = 0; s < 8; s++) {
        const int cid = s * 256 + tid;
        const int ml = cid >> 5, dc = (cid & 31) << 2;
        float4 v = *(const float4*)(ftile + ml * 132 + dc);
        *(float4*)(out + (size_t)(mtile + ml) * D + ntile + dc) = v;
    }
}

// ============================================================================
// scan_tr: fused scan + transpose (r4/r6-proven, pad 1026). 1024 thr = 16
// waves = 16 channels; transpose via LDS; midT [B,T,C] out.
// ============================================================================
__global__ __launch_bounds__(1024) void scan_tr_kernel(
    const _Float16* __restrict__ kc, const _Float16* __restrict__ vv,
    const _Float16* __restrict__ sr, const float* __restrict__ td,
    const float* __restrict__ tf, _Float16* __restrict__ midT)
{
    __shared__ _Float16 L[16 * 1026];
    const int tid = threadIdx.x;
    const int w = tid >> 6, lane = tid & 63;
    const int bq = blockIdx.x >> 6;
    const int c0 = (blockIdx.x & 63) << 4;
    const int c = c0 + w;
    const float wfac = expf(-expf(td[c]));
    const float ef = expf(tf[c]);
    const size_t base = (((size_t)(bq * C + c)) << 10) + lane * 16;

    half8 kA = *(const half8*)(kc + base), kB = *(const half8*)(kc + base + 8);
    half8 vA = *(const half8*)(vv + base), vB = *(const half8*)(vv + base + 8);
    half8 sA = *(const half8*)(sr + base), sB = *(const half8*)(sr + base + 8);
    float kcl[16], vl[16], srl[16];
#pragma unroll
    for (int i = 0; i < 8; i++) {
        kcl[i] = (float)kA[i]; kcl[8 + i] = (float)kB[i];
        vl[i]  = (float)vA[i]; vl[8 + i]  = (float)vB[i];
        srl[i] = (float)sA[i]; srl[8 + i] = (float)sB[i];
    }
    float ua = 0.f, ub = 0.f;
#pragma unroll
    for (int i = 0; i < 16; i++) {
        float kv = kcl[i] * vl[i];
        ua = fmaf(wfac, ua, kv);
        ub = fmaf(wfac, ub, kcl[i]);
    }
    float w2 = wfac * wfac, w4 = w2 * w2, w8 = w4 * w4, w16 = w8 * w8;
    float f = w16, sa = ua, sb = ub;
#pragma unroll
    for (int off = 1; off < 64; off <<= 1) {
        float pa = __shfl_up(sa, off);
        float pb = __shfl_up(sb, off);
        if (lane >= off) { sa = fmaf(f, pa, sa); sb = fmaf(f, pb, sb); }
        f = f * f;
    }
    float a0 = __shfl_up(sa, 1);
    float b0 = __shfl_up(sb, 1);
    if (lane == 0) { a0 = 0.f; b0 = 0.f; }
    half8 o0, o1;
#pragma unroll
    for (int i = 0; i < 16; i++) {
        float kv = kcl[i] * vl[i];
        float wkv = fmaf(ef, kv, a0);
        float wk = fmaf(ef, kcl[i], b0) + K_EPS;
        float o = srl[i] * (wkv / wk);
        if (i < 8) o0[i] = (_Float16)o; else o1[i - 8] = (_Float16)o;
        a0 = fmaf(wfac, a0, kv);
        b0 = fmaf(wfac, b0, kcl[i]);
    }
    *(half8*)(L + w * 1026 + lane * 16) = o0;
    *(half8*)(L + w * 1026 + lane * 16 + 8) = o1;
    __syncthreads();
    half8 g0, g1;
#pragma unroll
    for (int cc = 0; cc < 8; cc++)  g0[cc] = L[cc * 1026 + tid];
#pragma unroll
    for (int cc = 0; cc < 8; cc++)  g1[cc] = L[(cc + 8) * 1026 + tid];
    _Float16* dst = midT + (((size_t)(bq * T + tid)) << 10) + c0;
    *(half8*)(dst) = g0;
    *(half8*)(dst + 8) = g1;
}

extern "C" void kernel_launch(void* const* d_in, const int* in_sizes, int n_in,
                              void* d_out, int out_size, void* d_ws, size_t ws_size,
                              hipStream_t stream) {
    const float* xq  = (const float*)d_in[0];
    const float* td  = (const float*)d_in[3];
    const float* tf  = (const float*)d_in[4];
    const float* tmk = (const float*)d_in[5];
    const float* tmv = (const float*)d_in[6];
    const float* tmr = (const float*)d_in[7];
    const float* Wk  = (const float*)d_in[8];
    const float* Wv  = (const float*)d_in[9];
    const float* Wr  = (const float*)d_in[10];
    const float* Wo  = (const float*)d_in[11];
    float* out = (float*)d_out;

    const size_t MC = (size_t)M * C;
    char* ws = (char*)d_ws;
    _Float16* ak   = (_Float16*)(ws);
    _Float16* av   = (_Float16*)(ws + MC * 2);
    _Float16* ar   = (_Float16*)(ws + MC * 4);
    _Float16* wk16 = (_Float16*)(ws + MC * 6);
    _Float16* wv16 = wk16 + (size_t)D * C;
    _Float16* wr16 = wv16 + (size_t)D * C;
    _Float16* wo16 = wr16 + (size_t)D * C;
    _Float16* kc16 = (_Float16*)(ws + MC * 6 + (size_t)D * C * 8);
    _Float16* vv16 = kc16 + MC;
    _Float16* sr16 = vv16 + MC;
    _Float16* midT = ak;   // ak dead after gemm_in

    convert_kernel<<<dim3(8192), dim3(256), 0, stream>>>(
        xq, tmk, tmv, tmr, ak, av, ar, Wk, Wv, Wr, Wo, wk16, wv16, wr16, wo16);
    gemm_in_kernel<<<dim3(M / 256, 24), dim3(512), 0, stream>>>(
        ak, av, ar, wk16, wv16, wr16, kc16, vv16, sr16);
    scan_tr_kernel<<<dim3(B * C / 16), dim3(1024), 0, stream>>>(
        kc16, vv16, sr16, td, tf, midT);
    gemm_out_kernel<<<dim3(M / 64, D / 128), dim3(256), 0, stream>>>(
        midT, wo16, out);
}